// Round 18
// baseline (543.109 us; speedup 1.0000x reference)
//
#include <hip/hip_runtime.h>
#include <hip/hip_bf16.h>
#include <math.h>

typedef __attribute__((ext_vector_type(8))) short s16x8;
typedef __attribute__((ext_vector_type(4))) short s16x4;
typedef __attribute__((ext_vector_type(4))) float f32x4;

#define MPAD 4352   // = 34*128 = 17*256
#define LG 2064     // global seq length
#define CT 8        // k-tiles (of 64 keys) per split chunk
#define SM_SHIFT 11.5415603f  // 8 * log2(e); softmax = exp2(S*log2e - SM_SHIFT)

__device__ __forceinline__ short f2b(float f) {  // RNE (weights/activations)
  unsigned u = __float_as_uint(f);
  unsigned r = (u + 0x7fffu + ((u >> 16) & 1u)) >> 16;
  return (short)(unsigned short)r;
}
__device__ __forceinline__ float b2f(short s) {
  return __uint_as_float(((unsigned)(unsigned short)s) << 16);
}
__device__ __forceinline__ float fexp2(float x) {
#if __has_builtin(__builtin_amdgcn_exp2f)
  return __builtin_amdgcn_exp2f(x);
#else
  float r;
  asm("v_exp_f32 %0, %1" : "=v"(r) : "v"(x));
  return r;
#endif
}
__device__ __forceinline__ int cvtpk(float lo, float hi) {
  int r;
  asm("v_cvt_pk_bf16_f32 %0, %1, %2" : "=v"(r) : "v"(lo), "v"(hi));
  return r;
}

// global->LDS direct async copy, 16B per lane. LDS dest must be uniform-base + lane*16.
__device__ __forceinline__ void gl_lds16(const short* g, short* l) {
  __builtin_amdgcn_global_load_lds((const __attribute__((address_space(1))) short*)g,
                                   (__attribute__((address_space(3))) short*)l, 16, 0, 0);
}

// ---------------- transpose + cast: in f32 (K x N) -> out bf16 (N x K) ----------------
__global__ __launch_bounds__(256) void transpose_cast(const float* __restrict__ in,
                                                      short* __restrict__ out,
                                                      int K, int N) {
  __shared__ float tile[32][33];
  int bn = blockIdx.x * 32;
  int bk = blockIdx.y * 32;
  for (int i = threadIdx.y; i < 32; i += 8)
    tile[i][threadIdx.x] = in[(size_t)(bk + i) * N + bn + threadIdx.x];
  __syncthreads();
  for (int i = threadIdx.y; i < 32; i += 8)
    out[(size_t)(bn + i) * K + bk + threadIdx.x] = f2b(tile[threadIdx.x][i]);
}

// ---------------- V transpose: QKV V-slice -> Vt[s*16+h][64][Lpad]; covers FULL Lpad ----------------
__global__ __launch_bounds__(256) void transpose_v(const short* __restrict__ QKV,
                                                   short* __restrict__ Vt,
                                                   int L, int Lpad) {
  __shared__ short tile[32][33];
  int sh = blockIdx.z;
  int s = sh >> 4, h = sh & 15;
  int kb = blockIdx.x * 32;
  int cb = blockIdx.y * 32;
  int tx = threadIdx.x;
  for (int i = threadIdx.y; i < 32; i += 8) {
    int key = kb + i;
    if (key > L - 1) key = L - 1;
    tile[i][tx] = QKV[(size_t)(s * L + key) * 3072 + 2048 + h * 64 + cb + tx];
  }
  __syncthreads();
  for (int i = threadIdx.y; i < 32; i += 8)
    Vt[((size_t)sh * 64 + cb + i) * Lpad + kb + tx] = tile[tx][i];
}

// ================= 8-phase 256x256 GEMM (T3+T4 counted vmcnt, T2 swizzle, T5 setprio) ============
#define QROW(MI, AX)                                                                  \
  acc[MI][0] = __builtin_amdgcn_mfma_f32_16x16x32_bf16(AX, b0, acc[MI][0], 0, 0, 0);  \
  acc[MI][1] = __builtin_amdgcn_mfma_f32_16x16x32_bf16(AX, b1, acc[MI][1], 0, 0, 0);  \
  acc[MI][2] = __builtin_amdgcn_mfma_f32_16x16x32_bf16(AX, b2, acc[MI][2], 0, 0, 0);  \
  acc[MI][3] = __builtin_amdgcn_mfma_f32_16x16x32_bf16(AX, b3, acc[MI][3], 0, 0, 0);

#define RD12(B, S)                                                              \
  a0 = rdA(B, S, 0); a1 = rdA(B, S, 1); a2 = rdA(B, S, 2); a3 = rdA(B, S, 3);   \
  a4 = rdA(B, S, 4); a5 = rdA(B, S, 5); a6 = rdA(B, S, 6); a7 = rdA(B, S, 7);   \
  b0 = rdB(B, S, 0); b1 = rdB(B, S, 1); b2 = rdB(B, S, 2); b3 = rdB(B, S, 3);

__global__ __launch_bounds__(512, 2) void gemm_8ph(const short* __restrict__ A,
                                                   const short* __restrict__ BT,
                                                   short* __restrict__ C,
                                                   int K, int N) {
  extern __shared__ short lds[];      // 65536 shorts = 128KB
  short* Asb = lds;                   // [buf*2+half][8192]
  short* Bsb = lds + 32768;
  const int tid = threadIdx.x;
  const int lane = tid & 63, wid = tid >> 6;
  const int wm = wid >> 2, wn = wid & 3;  // 2 x 4 wave grid
  const int l15 = lane & 15, lhi = lane >> 4;
  const int m0 = blockIdx.y * 256;
  const int n0 = blockIdx.x * 256;

  f32x4 acc[8][4] = {};

  auto stageA = [&](int b, int h, int kt) {
#pragma unroll
    for (int j = 0; j < 2; ++j) {
      int u = j * 512 + tid;          // 0..1023
      int row = u >> 3, slot = u & 7;
      int ss = slot ^ (row & 7);      // inverse swizzle on source (involution)
      gl_lds16(A + (size_t)(m0 + h * 128 + row) * K + kt * 64 + ss * 8,
               Asb + (b * 2 + h) * 8192 + u * 8);
    }
  };
  auto stageB = [&](int b, int h, int kt) {
#pragma unroll
    for (int j = 0; j < 2; ++j) {
      int u = j * 512 + tid;
      int row = u >> 3, slot = u & 7;
      int ss = slot ^ (row & 7);
      gl_lds16(BT + (size_t)(n0 + h * 128 + row) * K + kt * 64 + ss * 8,
               Bsb + (b * 2 + h) * 8192 + u * 8);
    }
  };
  auto rdA = [&](int b, int s, int mf) -> s16x8 {
    int row = mf * 16 + l15;
    int sl = ((s << 2) | lhi) ^ (row & 7);
    return *(const s16x8*)(Asb + (b * 2 + wm) * 8192 + row * 64 + sl * 8);
  };
  auto rdB = [&](int b, int s, int nf) -> s16x8 {
    int row = (wn & 1) * 64 + nf * 16 + l15;
    int sl = ((s << 2) | lhi) ^ (row & 7);
    return *(const s16x8*)(Bsb + (b * 2 + (wn >> 1)) * 8192 + row * 64 + sl * 8);
  };

  const int NT = K >> 7;  // iterations; 2 K-tiles (BK=64) each

  stageA(0, 0, 0); stageA(0, 1, 0); stageB(0, 0, 0); stageB(0, 1, 0);
  stageA(1, 0, 1); stageA(1, 1, 1);
  asm volatile("s_waitcnt vmcnt(4)" ::: "memory");
  __builtin_amdgcn_s_barrier();

  s16x8 a0, a1, a2, a3, a4, a5, a6, a7, b0, b1, b2, b3;

  for (int t = 0; t < NT; ++t) {
    const bool last = (t == NT - 1);
    const int kt1 = 2 * t + 1;
    RD12(0, 0)
    stageB(1, 0, kt1);
    __builtin_amdgcn_s_barrier();
    __builtin_amdgcn_s_setprio(1);
    QROW(0, a0) QROW(1, a1) QROW(2, a2) QROW(3, a3)
    __builtin_amdgcn_s_setprio(0);
    __builtin_amdgcn_s_barrier();
    stageB(1, 1, kt1);
    __builtin_amdgcn_s_barrier();
    __builtin_amdgcn_s_setprio(1);
    QROW(4, a4) QROW(5, a5) QROW(6, a6) QROW(7, a7)
    __builtin_amdgcn_s_setprio(0);
    __builtin_amdgcn_s_barrier();
    RD12(0, 1)
    __builtin_amdgcn_s_barrier();
    __builtin_amdgcn_s_setprio(1);
    QROW(0, a0) QROW(1, a1) QROW(2, a2) QROW(3, a3)
    __builtin_amdgcn_s_setprio(0);
    __builtin_amdgcn_s_barrier();
    if (!last) {
      stageA(0, 0, 2 * t + 2); stageA(0, 1, 2 * t + 2);
      asm volatile("s_waitcnt vmcnt(4)" ::: "memory");
    } else {
      asm volatile("s_waitcnt vmcnt(0)" ::: "memory");
    }
    __builtin_amdgcn_s_barrier();
    __builtin_amdgcn_s_setprio(1);
    QROW(4, a4) QROW(5, a5) QROW(6, a6) QROW(7, a7)
    __builtin_amdgcn_s_setprio(0);
    __builtin_amdgcn_s_barrier();
    RD12(1, 0)
    if (!last) stageB(0, 0, 2 * t + 2);
    __builtin_amdgcn_s_barrier();
    __builtin_amdgcn_s_setprio(1);
    QROW(0, a0) QROW(1, a1) QROW(2, a2) QROW(3, a3)
    __builtin_amdgcn_s_setprio(0);
    __builtin_amdgcn_s_barrier();
    if (!last) stageB(0, 1, 2 * t + 2);
    __builtin_amdgcn_s_barrier();
    __builtin_amdgcn_s_setprio(1);
    QROW(4, a4) QROW(5, a5) QROW(6, a6) QROW(7, a7)
    __builtin_amdgcn_s_setprio(0);
    __builtin_amdgcn_s_barrier();
    RD12(1, 1)
    __builtin_amdgcn_s_barrier();
    __builtin_amdgcn_s_setprio(1);
    QROW(0, a0) QROW(1, a1) QROW(2, a2) QROW(3, a3)
    __builtin_amdgcn_s_setprio(0);
    __builtin_amdgcn_s_barrier();
    if (!last) {
      stageA(1, 0, kt1 + 2); stageA(1, 1, kt1 + 2);
      asm volatile("s_waitcnt vmcnt(4)" ::: "memory");
    }
    __builtin_amdgcn_s_barrier();
    __builtin_amdgcn_s_setprio(1);
    QROW(4, a4) QROW(5, a5) QROW(6, a6) QROW(7, a7)
    __builtin_amdgcn_s_setprio(0);
    __builtin_amdgcn_s_barrier();
  }

#pragma unroll
  for (int mf = 0; mf < 8; ++mf) {
    int row_base = m0 + wm * 128 + mf * 16 + lhi * 4;
#pragma unroll
    for (int nf = 0; nf < 4; ++nf) {
      int col = n0 + wn * 64 + nf * 16 + l15;
#pragma unroll
      for (int r = 0; r < 4; ++r)
        C[(size_t)(row_base + r) * N + col] = f2b(acc[mf][nf][r]);
    }
  }
}

// ---------------- GEMM v3 (2-phase prefetch; used for proj N=1024) ----------------
__global__ __launch_bounds__(256) void gemm_bt3(const short* __restrict__ A,
                                                const short* __restrict__ BT,
                                                short* __restrict__ C,
                                                int K, int N) {
  __shared__ short As[2][128 * 32];
  __shared__ short Bs[2][128 * 32];
  const int tid = threadIdx.x;
  const int lane = tid & 63;
  const int w = tid >> 6;
  const int wr = (w >> 1) * 64, wc = (w & 1) * 64;
  const int m0 = blockIdx.y * 128;
  const int n0 = blockIdx.x * 128;
  const int l15 = lane & 15, lhi = lane >> 4;

  f32x4 acc[4][4] = {};

  auto STAGE = [&](int b, int k0) {
#pragma unroll
    for (int p = 0; p < 2; ++p) {
      int g = w * 128 + p * 64 + lane;
      int row = g >> 2;
      int cs = (g & 3) * 8;
      gl_lds16(A + (size_t)(m0 + row) * K + k0 + cs, &As[b][g * 8]);
      gl_lds16(BT + (size_t)(n0 + row) * K + k0 + cs, &Bs[b][g * 8]);
    }
  };

  const int nt = K >> 5;
  STAGE(0, 0);
  __syncthreads();
  int cur = 0;
  for (int t = 0; t < nt; ++t) {
    if (t + 1 < nt) STAGE(cur ^ 1, (t + 1) << 5);
    s16x8 af[4], bf[4];
#pragma unroll
    for (int m = 0; m < 4; ++m)
      af[m] = *(const s16x8*)(&As[cur][(wr + m * 16 + l15) * 32 + lhi * 8]);
#pragma unroll
    for (int n = 0; n < 4; ++n)
      bf[n] = *(const s16x8*)(&Bs[cur][(wc + n * 16 + l15) * 32 + lhi * 8]);
#pragma unroll
    for (int m = 0; m < 4; ++m)
#pragma unroll
      for (int n = 0; n < 4; ++n)
        acc[m][n] = __builtin_amdgcn_mfma_f32_16x16x32_bf16(af[m], bf[n], acc[m][n], 0, 0, 0);
    __syncthreads();
    cur ^= 1;
  }
#pragma unroll
  for (int m = 0; m < 4; ++m) {
    int row_base = m0 + wr + m * 16 + lhi * 4;
#pragma unroll
    for (int n = 0; n < 4; ++n) {
      int col = n0 + wc + n * 16 + l15;
#pragma unroll
      for (int r = 0; r < 4; ++r)
        C[(size_t)(row_base + r) * N + col] = f2b(acc[m][n][r]);
    }
  }
}

// ---------------- RMSNorm on Q (with 1/8*log2e scale) and K slices of QKV, in place ----------------
__global__ __launch_bounds__(256) void rmsnorm_qk(short* __restrict__ QKV,
                                                  const float* __restrict__ g) {
  int row = blockIdx.x;
  int which = blockIdx.y;  // 0 = q, 1 = k
  size_t base = (size_t)row * 3072 + (size_t)which * 1024;
  int t = threadIdx.x;
  s16x4 in = *(const s16x4*)(QKV + base + t * 4);
  float v[4];
  float ss = 0.f;
#pragma unroll
  for (int j = 0; j < 4; ++j) {
    v[j] = b2f(in[j]);
    ss += v[j] * v[j];
  }
#pragma unroll
  for (int m = 32; m >= 1; m >>= 1) ss += __shfl_xor(ss, m);
  __shared__ float red[4];
  if ((t & 63) == 0) red[t >> 6] = ss;
  __syncthreads();
  float tot = red[0] + red[1] + red[2] + red[3];
  float inv = rsqrtf(tot * (1.0f / 1024.0f) + 1e-6f);
  if (which == 0) inv *= 0.125f * 1.44269504f;  // fold 1/sqrt(hd) AND log2(e) into Q
  s16x4 out;
#pragma unroll
  for (int j = 0; j < 4; ++j) out[j] = f2b(v[j] * inv * g[t * 4 + j]);
  *(s16x4*)(&QKV[base + t * 4]) = out;
}

// ======== swapped-operand attention (R16-proven per-wave body) ========
// QK^T computed as mfma(K, Q); P->bf16 via v_cvt_pk; PV A-fragment via 16 __shfl.
// Ks/Vs double-buffered, ONE barrier per iter, prefetch issued AFTER the barrier.

// ---------------- causal flash attention (local, QBLK=64, 4 waves) — R16 VERBATIM ----------------
__global__ __launch_bounds__(256) void attn_causal4(const short* __restrict__ QKV,
                                                    const short* __restrict__ Vt,
                                                    short* __restrict__ Y,
                                                    int L, int Lpad) {
  const int h = blockIdx.y, s = blockIdx.z;
  const int q0 = (gridDim.x - 1 - blockIdx.x) * 64;  // LPT: longest first
  const int tid = threadIdx.x;
  const int lane = tid & 63, w = tid >> 6;
  const int l15 = lane & 15, lhi = lane >> 4;
  const int row0 = s * L;

  __shared__ short Ks[2][64][72];
  __shared__ short Vs[2][64][72];

  int qld = q0 + w * 16 + l15;
  if (qld > L - 1) qld = L - 1;
  const size_t qrow = (size_t)(row0 + qld) * 3072 + h * 64;
  s16x8 qf0 = *(const s16x8*)(QKV + qrow + lhi * 8);
  s16x8 qf1 = *(const s16x8*)(QKV + qrow + 32 + lhi * 8);

  float lsum = 0.f;
  f32x4 o[4];
#pragma unroll
  for (int d = 0; d < 4; ++d) o[d] = f32x4{0.f, 0.f, 0.f, 0.f};

  const short* Vbase = Vt + (size_t)(s * 16 + h) * 64 * Lpad;
  const int sA = (lhi & 1) * 32 + l15;
  const int sB = sA + 16;
  const int bh = lhi >> 1;

  s16x8 kreg[2], vreg[2];
#pragma unroll
  for (int p = 0; p < 2; ++p) {
    int g = tid + p * 256;
    int kr = g >> 3, cs = (g & 7) * 8;
    int krow = kr;
    if (krow > L - 1) krow = L - 1;
    kreg[p] = *(const s16x8*)(QKV + (size_t)(row0 + krow) * 3072 + 1024 + h * 64 + cs);
    vreg[p] = *(const s16x8*)(Vbase + (size_t)kr * Lpad + cs);
  }

  int buf = 0;
  for (int kb = 0; kb <= q0; kb += 64, buf ^= 1) {
#pragma unroll
    for (int p = 0; p < 2; ++p) {
      int g = tid + p * 256;
      int kr = g >> 3, cs = (g & 7) * 8;
      *(s16x8*)(&Ks[buf][kr][cs]) = kreg[p];
      *(s16x8*)(&Vs[buf][kr][cs]) = vreg[p];
    }
    __syncthreads();
    if (kb + 64 <= q0) {  // prefetch AFTER barrier: in flight across compute
#pragma unroll
      for (int p = 0; p < 2; ++p) {
        int g = tid + p * 256;
        int kr = g >> 3, cs = (g & 7) * 8;
        int krow = kb + 64 + kr;
        if (krow > L - 1) krow = L - 1;
        kreg[p] = *(const s16x8*)(QKV + (size_t)(row0 + krow) * 3072 + 1024 + h * 64 + cs);
        vreg[p] = *(const s16x8*)(Vbase + (size_t)kr * Lpad + kb + 64 + cs);
      }
    }

    // S^T = K Q^T (swapped operands)
    f32x4 st[4];
#pragma unroll
    for (int n = 0; n < 4; ++n) {
      s16x8 k0 = *(const s16x8*)(&Ks[buf][n * 16 + l15][lhi * 8]);
      s16x8 k1 = *(const s16x8*)(&Ks[buf][n * 16 + l15][32 + lhi * 8]);
      f32x4 sa = f32x4{-SM_SHIFT, -SM_SHIFT, -SM_SHIFT, -SM_SHIFT};
      sa = __builtin_amdgcn_mfma_f32_16x16x32_bf16(k0, qf0, sa, 0, 0, 0);
      sa = __builtin_amdgcn_mfma_f32_16x16x32_bf16(k1, qf1, sa, 0, 0, 0);
      st[n] = sa;
    }

    if (kb == q0) {  // diagonal tile mask: key > q
      int q = q0 + w * 16 + l15;
#pragma unroll
      for (int n = 0; n < 4; ++n) {
#pragma unroll
        for (int r = 0; r < 4; ++r) {
          int key = kb + n * 16 + lhi * 4 + r;
          if (key > q) st[n][r] = -1e30f;
        }
      }
    }

    int wd[4][2];
#pragma unroll
    for (int n = 0; n < 4; ++n) {
      float p0 = fexp2(st[n][0]), p1 = fexp2(st[n][1]);
      float p2 = fexp2(st[n][2]), p3 = fexp2(st[n][3]);
      lsum += (p0 + p1) + (p2 + p3);
      wd[n][0] = cvtpk(p0, p1);
      wd[n][1] = cvtpk(p2, p3);
    }

#pragma unroll
    for (int kk = 0; kk < 2; ++kk) {
      int a0 = __shfl(wd[2 * kk][0], sA), a1 = __shfl(wd[2 * kk][1], sA);
      int a2 = __shfl(wd[2 * kk][0], sB), a3 = __shfl(wd[2 * kk][1], sB);
      int c0 = __shfl(wd[2 * kk + 1][0], sA), c1 = __shfl(wd[2 * kk + 1][1], sA);
      int c2 = __shfl(wd[2 * kk + 1][0], sB), c3 = __shfl(wd[2 * kk + 1][1], sB);
      int pw[4];
      pw[0] = bh ? c0 : a0;
      pw[1] = bh ? c1 : a1;
      pw[2] = bh ? c2 : a2;
      pw[3] = bh ? c3 : a3;
      s16x8 pa = *(const s16x8*)pw;
#pragma unroll
      for (int d = 0; d < 4; ++d) {
        s16x8 vf = *(const s16x8*)(&Vs[buf][d * 16 + l15][kk * 32 + lhi * 8]);
        o[d] = __builtin_amdgcn_mfma_f32_16x16x32_bf16(pa, vf, o[d], 0, 0, 0);
      }
    }
  }

  lsum += __shfl_xor(lsum, 16);
  lsum += __shfl_xor(lsum, 32);
  float lsq[4];
#pragma unroll
  for (int r = 0; r < 4; ++r) lsq[r] = __shfl(lsum, lhi * 4 + r);
#pragma unroll
  for (int d = 0; d < 4; ++d) {
#pragma unroll
    for (int r = 0; r < 4; ++r) {
      int qr = q0 + w * 16 + lhi * 4 + r;
      if (qr < L)
        Y[(size_t)(row0 + qr) * 1024 + h * 64 + d * 16 + l15] = f2b(o[d][r] / lsq[r]);
    }
  }
}

// ---------------- split-K causal attention (global), 8 waves / QBLK=128 ----------------
// Per-wave body VERBATIM from the proven R16 kernel (each wave still owns 16 q-rows).
// Changes: 512 threads (w 0..7, qw = q0 + w*16), one staging chunk per thread, tile
// bounds for the 128-row block, mask trigger kb+63 > qw (mask BODY unchanged & exact).
__global__ __launch_bounds__(512) void attn_split8(const short* __restrict__ QKV,
                                                   const short* __restrict__ Vt,
                                                   float* __restrict__ o_acc,
                                                   float* __restrict__ ls_acc) {
  const int qb = gridDim.x - 1 - blockIdx.x;  // LPT: longest first (0..16)
  const int chunk = blockIdx.y;
  const int sh = blockIdx.z;
  const int q0 = qb * 128;
  const int tiles = (min(q0 + 127, LG - 1) >> 6) + 1;
  const int t0 = chunk * CT;
  if (t0 >= tiles) return;
  const int t1 = min(t0 + CT, tiles);
  const int h = sh & 15, s = sh >> 4;
  const int tid = threadIdx.x;
  const int lane = tid & 63, w = tid >> 6;  // w 0..7
  const int l15 = lane & 15, lhi = lane >> 4;
  const int row0 = s * LG;
  const int Lpad = 2112;
  const int qw = q0 + w * 16;

  __shared__ short Ks[2][64][72];
  __shared__ short Vs[2][64][72];

  int qld = qw + l15;
  if (qld > LG - 1) qld = LG - 1;
  const size_t qrow = (size_t)(row0 + qld) * 3072 + h * 64;
  s16x8 qf0 = *(const s16x8*)(QKV + qrow + lhi * 8);
  s16x8 qf1 = *(const s16x8*)(QKV + qrow + 32 + lhi * 8);

  float lsum = 0.f;
  f32x4 o[4];
#pragma unroll
  for (int d = 0; d < 4; ++d) o[d] = f32x4{0.f, 0.f, 0.f, 0.f};

  const short* Vbase = Vt + (size_t)sh * 64 * Lpad;
  const int sA = (lhi & 1) * 32 + l15;
  const int sB = sA + 16;
  const int bh = lhi >> 1;

  // staging: 512 chunks (64 rows x 8 slots of 8 shorts), ONE chunk per thread
  s16x8 kreg, vreg;
  const int skr = tid >> 3, scs = (tid & 7) * 8;
  {
    int krow = t0 * 64 + skr;
    if (krow > LG - 1) krow = LG - 1;
    kreg = *(const s16x8*)(QKV + (size_t)(row0 + krow) * 3072 + 1024 + h * 64 + scs);
    vreg = *(const s16x8*)(Vbase + (size_t)skr * Lpad + t0 * 64 + scs);
  }

  int buf = 0;
  for (int t = t0; t < t1; ++t, buf ^= 1) {
    const int kb = t * 64;
    *(s16x8*)(&Ks[buf][skr][scs]) = kreg;
    *(s16x8*)(&Vs[buf][skr][scs]) = vreg;
    __syncthreads();
    if (t + 1 < t1) {  // prefetch AFTER barrier
      int krow = kb + 64 + skr;
      if (krow > LG - 1) krow = LG - 1;
      kreg = *(const s16x8*)(QKV + (size_t)(row0 + krow) * 3072 + 1024 + h * 64 + scs);
      vreg = *(const s16x8*)(Vbase + (size_t)skr * Lpad + kb + 64 + scs);
    }

    f32x4 st[4];
#pragma unroll
    for (int n = 0; n < 4; ++n) {
      s16x8 k0 = *(const s16x8*)(&Ks[buf][n * 16 + l15][lhi * 8]);
      s16x8 k1 = *(const s16x8*)(&Ks[buf][n * 16 + l15][32 + lhi * 8]);
      f32x4 sa = f32x4{-SM_SHIFT, -SM_SHIFT, -SM_SHIFT, -SM_SHIFT};
      sa = __builtin_amdgcn_mfma_f32_16x16x32_bf16(k0, qf0, sa, 0, 0, 0);
      sa = __builtin_amdgcn_mfma_f32_16x16x32_bf16(k1, qf1, sa, 0, 0, 0);
      st[n] = sa;
    }

    if (kb + 63 > qw) {  // partially/fully masked tile for THIS wave (exact per-key mask)
      int q = qw + l15;
#pragma unroll
      for (int n = 0; n < 4; ++n) {
#pragma unroll
        for (int r = 0; r < 4; ++r) {
          int key = kb + n * 16 + lhi * 4 + r;
          if (key > q) st[n][r] = -1e30f;
        }
      }
    }

    int wd[4][2];
#pragma unroll
    for (int n = 0; n < 4; ++n) {
      float p0 = fexp2(st[n][0]), p1 = fexp2(st[n][1]);
      float p2 = fexp2(st[n][2]), p3 = fexp2(st[n][3]);
      lsum += (p0 + p1) + (p2 + p3);
      wd[n][0] = cvtpk(p0, p1);
      wd[n][1] = cvtpk(p2, p3);
    }

#pragma unroll
    for (int kk = 0; kk < 2; ++kk) {
      int a0 = __shfl(wd[2 * kk][0], sA), a1 = __shfl(wd[2 * kk][1], sA);
      int a2 = __shfl(wd[2 * kk][0], sB), a3 = __shfl(wd[2 * kk][1], sB);
      int c0 = __shfl(wd[2 * kk + 1][0], sA), c1 = __shfl(wd[2 * kk + 1][1], sA);
      int c2 = __shfl(wd[2 * kk + 1][0], sB), c3 = __shfl(wd[2 * kk + 1][1], sB);
      int pw[4];
      pw[0] = bh ? c0 : a0;
      pw[1] = bh ? c1 : a1;
      pw[2] = bh ? c2 : a2;
      pw[3] = bh ? c3 : a3;
      s16x8 pa = *(const s16x8*)pw;
#pragma unroll
      for (int d = 0; d < 4; ++d) {
        s16x8 vf = *(const s16x8*)(&Vs[buf][d * 16 + l15][kk * 32 + lhi * 8]);
        o[d] = __builtin_amdgcn_mfma_f32_16x16x32_bf16(pa, vf, o[d], 0, 0, 0);
      }
    }
  }

  lsum += __shfl_xor(lsum, 16);
  lsum += __shfl_xor(lsum, 32);
  int qmy = qw + l15;
  if (lhi == 0 && qmy < LG) atomicAdd(&ls_acc[(size_t)sh * LG + qmy], lsum);
#pragma unroll
  for (int r = 0; r < 4; ++r) {
    int qr = qw + lhi * 4 + r;
    if (qr < LG) {
#pragma unroll
      for (int d = 0; d < 4; ++d)
        atomicAdd(&o_acc[((size_t)sh * LG + qr) * 64 + d * 16 + l15], o[d][r]);
    }
  }
}

// merge: Y = o_acc / ls_acc
__global__ __launch_bounds__(256) void attn_merge(const float* __restrict__ o_acc,
                                                  const float* __restrict__ ls_acc,
                                                  short* __restrict__ Y) {
  int sh = blockIdx.z * 16 + blockIdx.y;
  int s = sh >> 4, h = sh & 15;
  int row = blockIdx.x * 4 + (threadIdx.x >> 6);
  int col = threadIdx.x & 63;
  if (row < LG) {
    float inv = 1.0f / ls_acc[(size_t)sh * LG + row];
    float v = o_acc[((size_t)sh * LG + row) * 64 + col];
    Y[(size_t)(s * LG + row) * 1024 + h * 64 + col] = f2b(v * inv);
  }
}

// ---------------- fused gather/scatter ----------------
__global__ __launch_bounds__(256) void build_xl(const float* __restrict__ x,
                                                const float* __restrict__ lm,
                                                short* __restrict__ Xin) {
  int row = blockIdx.x;  // 0..4351
  int s = row / 272, r = row % 272;
  const float* src = (r < 16) ? lm + ((size_t)s * 16 + r) * 1024
                              : x + ((size_t)s * 256 + (r - 16)) * 1024;
  int t = threadIdx.x;
  f32x4 v = *(const f32x4*)(src + t * 4);
  s16x4 o;
#pragma unroll
  for (int j = 0; j < 4; ++j) o[j] = f2b(v[j]);
  *(s16x4*)(&Xin[(size_t)row * 1024 + t * 4]) = o;
}

__global__ __launch_bounds__(256) void split_local_build_xg(const short* __restrict__ Pout,
                                                            const float* __restrict__ mem_src,
                                                            float* __restrict__ lm_out,
                                                            short* __restrict__ Xin) {
  int row = blockIdx.x;
  int t = threadIdx.x;
  if (row < 4352) {
    int sr = row < 4128 ? row : 4127;
    int b = sr / 2064, r = sr % 2064;
    s16x4 o;
    if (r < 16) {
      f32x4 v = *(const f32x4*)(mem_src + ((size_t)(b * 16 + r)) * 1024 + t * 4);
#pragma unroll
      for (int j = 0; j < 4; ++j) o[j] = f2b(v[j]);
    } else {
      int f = b * 2048 + (r - 16);
      int pr = (f >> 8) * 272 + 16 + (f & 255);
      o = *(const s16x4*)(Pout + (size_t)pr * 1024 + t * 4);
    }
    *(s16x4*)(&Xin[(size_t)row * 1024 + t * 4]) = o;
  } else {
    int m = row - 4352;
    int pr = (m >> 4) * 272 + (m & 15);
    s16x4 v = *(const s16x4*)(Pout + (size_t)pr * 1024 + t * 4);
    f32x4 o;
#pragma unroll
    for (int j = 0; j < 4; ++j) o[j] = b2f(v[j]);
    *(f32x4*)(&lm_out[(size_t)m * 1024 + t * 4]) = o;
  }
}

__global__ __launch_bounds__(256) void split_global_build_xl(const short* __restrict__ Pout,
                                                             const float* __restrict__ lm_src,
                                                             float* __restrict__ mem_out,
                                                             short* __restrict__ Xin) {
  int row = blockIdx.x;
  int t = threadIdx.x;
  if (row < 4352) {
    int s = row / 272, r = row % 272;
    s16x4 o;
    if (r < 16) {
      f32x4 v = *(const f32x4*)(lm_src + ((size_t)(s * 16 + r)) * 1024 + t * 4);
#pragma unroll
      for (int j = 0; j < 4; ++j) o[j] = f2b(v[j]);
    } else {
      int f = s * 256 + (r - 16);
      int pr = (f >> 11) * 2064 + 16 + (f & 2047);
      o = *(const s16x4*)(Pout + (size_t)pr * 1024 + t * 4);
    }
    *(s16x4*)(&Xin[(size_t)row * 1024 + t * 4]) = o;
  } else {
    int m = row - 4352;
    int pr = (m >> 4) * 2064 + (m & 15);
    s16x4 v = *(const s16x4*)(Pout + (size_t)pr * 1024 + t * 4);
    f32x4 o;
#pragma unroll
    for (int j = 0; j < 4; ++j) o[j] = b2f(v[j]);
    *(f32x4*)(&mem_out[(size_t)m * 1024 + t * 4]) = o;
  }
}

__global__ __launch_bounds__(256) void split_global_final(const short* __restrict__ Pout,
                                                          float* __restrict__ out) {
  int f = blockIdx.x;
  int t = threadIdx.x;
  int pr = (f >> 11) * 2064 + 16 + (f & 2047);
  s16x4 v = *(const s16x4*)(Pout + (size_t)pr * 1024 + t * 4);
  f32x4 o;
#pragma unroll
  for (int j = 0; j < 4; ++j) o[j] = b2f(v[j]);
  *(f32x4*)(&out[(size_t)f * 1024 + t * 4]) = o;
}

// ---------------- orchestration ----------------
extern "C" void kernel_launch(void* const* d_in, const int* in_sizes, int n_in,
                              void* d_out, int out_size, void* d_ws, size_t ws_size,
                              hipStream_t stream) {
  const float* x_in = (const float*)d_in[0];
  const float* mem_in = (const float*)d_in[1];
  const float* lm_in = (const float*)d_in[2];
  const float* Wqkv_loc = (const float*)d_in[3];
  const float* Wproj_loc = (const float*)d_in[4];
  const float* g_loc = (const float*)d_in[5];
  const float* Wqkv_glob = (const float*)d_in[6];
  const float* Wproj_glob = (const float*)d_in[7];
  const float* g_glob = (const float*)d_in[8];

  static bool attr_set = false;
  if (!attr_set) {
    hipFuncSetAttribute((const void*)gemm_8ph,
                        hipFuncAttributeMaxDynamicSharedMemorySize, 131072);
    attr_set = true;
  }

  char* ws = (char*)d_ws;
  size_t off = 0;
  auto alloc = [&](size_t bytes) {
    char* p = ws + off;
    off += (bytes + 255) & ~(size_t)255;
    return p;
  };
  short* Wt = (short*)alloc((size_t)3072 * 1024 * 2);
  float* lm_cur = (float*)alloc((size_t)256 * 1024 * 4);
  float* mem_cur = (float*)alloc((size_t)32 * 1024 * 4);
  short* Xin = (short*)alloc((size_t)MPAD * 1024 * 2);
  short* QKVb = (short*)alloc((size_t)MPAD * 3072 * 2);
  short* Yb = (short*)alloc((size_t)MPAD * 1024 * 2);
  short* Pout = (short*)alloc((size_t)MPAD * 1024 * 2);
  short* Vtb = (short*)alloc((size_t)256 * 64 * 320 * 2);
  size_t oacc_bytes = (size_t)32 * LG * 64 * 4;
  size_t lacc_bytes = (size_t)32 * LG * 4;
  float* o_acc = (float*)alloc(oacc_bytes);
  float* ls_acc = (float*)alloc(lacc_bytes);
  const bool use_split = (ws_size >= off);

  for (int i = 0; i < 2; ++i) {
    // ---- local attention (16 seqs, L=272, rows = 4352 = MPAD) ----
    transpose_cast<<<dim3(96, 32), dim3(32, 8), 0, stream>>>(
        Wqkv_loc + (size_t)i * 1024 * 3072, Wt, 1024, 3072);
    if (i == 0) build_xl<<<4352, 256, 0, stream>>>(x_in, lm_in, Xin);
    gemm_8ph<<<dim3(12, 17), 512, 131072, stream>>>(Xin, Wt, QKVb, 1024, 3072);
    rmsnorm_qk<<<dim3(4352, 2), 256, 0, stream>>>(QKVb, g_loc + (size_t)i * 1024);
    transpose_v<<<dim3(10, 2, 256), dim3(32, 8), 0, stream>>>(QKVb, Vtb, 272, 320);
    attn_causal4<<<dim3(5, 16, 16), 256, 0, stream>>>(QKVb, Vtb, Yb, 272, 320);
    transpose_cast<<<dim3(32, 32), dim3(32, 8), 0, stream>>>(
        Wproj_loc + (size_t)i * 1024 * 1024, Wt, 1024, 1024);
    gemm_bt3<<<dim3(8, 34), 256, 0, stream>>>(Yb, Wt, Pout, 1024, 1024);
    split_local_build_xg<<<4608, 256, 0, stream>>>(Pout, i == 0 ? mem_in : mem_cur,
                                                   lm_cur, Xin);

    // ---- global attention (2 seqs, L=2064, rows = 4128; pads deterministic) ----
    transpose_cast<<<dim3(96, 32), dim3(32, 8), 0, stream>>>(
        Wqkv_glob + (size_t)i * 1024 * 3072, Wt, 1024, 3072);
    gemm_8ph<<<dim3(12, 17), 512, 131072, stream>>>(Xin, Wt, QKVb, 1024, 3072);
    rmsnorm_qk<<<dim3(4128, 2), 256, 0, stream>>>(QKVb, g_glob + (size_t)i * 1024);
    transpose_v<<<dim3(66, 2, 32), dim3(32, 8), 0, stream>>>(QKVb, Vtb, 2064, 2112);
    if (use_split) {
      hipMemsetAsync(o_acc, 0, oacc_bytes, stream);
      hipMemsetAsync(ls_acc, 0, lacc_bytes, stream);
      attn_split8<<<dim3(17, 5, 32), 512, 0, stream>>>(QKVb, Vtb, o_acc, ls_acc);
      attn_merge<<<dim3(516, 16, 2), 256, 0, stream>>>(o_acc, ls_acc, Yb);
    } else {
      attn_causal4<<<dim3(33, 16, 2), 256, 0, stream>>>(QKVb, Vtb, Yb, 2064, 2112);
    }
    transpose_cast<<<dim3(32, 32), dim3(32, 8), 0, stream>>>(
        Wproj_glob + (size_t)i * 1024 * 1024, Wt, 1024, 1024);
    gemm_bt3<<<dim3(8, 34), 256, 0, stream>>>(Yb, Wt, Pout, 1024, 1024);
    if (i == 0)
      split_global_build_xl<<<4384, 256, 0, stream>>>(Pout, lm_cur, mem_cur, Xin);
    else
      split_global_final<<<4096, 256, 0, stream>>>(Pout, (float*)d_out);
  }
}

// Round 19
// 529.889 us; speedup vs baseline: 1.0249x; 1.0249x over previous
//
#include <hip/hip_runtime.h>
#include <hip/hip_bf16.h>
#include <math.h>

typedef __attribute__((ext_vector_type(8))) short s16x8;
typedef __attribute__((ext_vector_type(4))) short s16x4;
typedef __attribute__((ext_vector_type(4))) float f32x4;

#define MPAD 4352   // = 34*128 = 17*256
#define LG 2064     // global seq length
#define CT 8        // k-tiles (of 64 keys) per split chunk
#define SM_SHIFT 11.5415603f  // 8 * log2(e); softmax = exp2(S*log2e - SM_SHIFT)

__device__ __forceinline__ short f2b(float f) {  // RNE (weights/activations)
  unsigned u = __float_as_uint(f);
  unsigned r = (u + 0x7fffu + ((u >> 16) & 1u)) >> 16;
  return (short)(unsigned short)r;
}
__device__ __forceinline__ float b2f(short s) {
  return __uint_as_float(((unsigned)(unsigned short)s) << 16);
}
__device__ __forceinline__ float fexp2(float x) {
#if __has_builtin(__builtin_amdgcn_exp2f)
  return __builtin_amdgcn_exp2f(x);
#else
  float r;
  asm("v_exp_f32 %0, %1" : "=v"(r) : "v"(x));
  return r;
#endif
}
__device__ __forceinline__ int cvtpk(float lo, float hi) {
  int r;
  asm("v_cvt_pk_bf16_f32 %0, %1, %2" : "=v"(r) : "v"(lo), "v"(hi));
  return r;
}

// global->LDS direct async copy, 16B per lane. LDS dest must be uniform-base + lane*16.
__device__ __forceinline__ void gl_lds16(const short* g, short* l) {
  __builtin_amdgcn_global_load_lds((const __attribute__((address_space(1))) short*)g,
                                   (__attribute__((address_space(3))) short*)l, 16, 0, 0);
}

// ---------------- transpose + cast: in f32 (K x N) -> out bf16 (N x K) ----------------
__global__ __launch_bounds__(256) void transpose_cast(const float* __restrict__ in,
                                                      short* __restrict__ out,
                                                      int K, int N) {
  __shared__ float tile[32][33];
  int bn = blockIdx.x * 32;
  int bk = blockIdx.y * 32;
  for (int i = threadIdx.y; i < 32; i += 8)
    tile[i][threadIdx.x] = in[(size_t)(bk + i) * N + bn + threadIdx.x];
  __syncthreads();
  for (int i = threadIdx.y; i < 32; i += 8)
    out[(size_t)(bn + i) * K + bk + threadIdx.x] = f2b(tile[threadIdx.x][i]);
}

// ---------------- V transpose: QKV V-slice -> Vt[s*16+h][64][Lpad]; covers FULL Lpad ----------------
__global__ __launch_bounds__(256) void transpose_v(const short* __restrict__ QKV,
                                                   short* __restrict__ Vt,
                                                   int L, int Lpad) {
  __shared__ short tile[32][33];
  int sh = blockIdx.z;
  int s = sh >> 4, h = sh & 15;
  int kb = blockIdx.x * 32;
  int cb = blockIdx.y * 32;
  int tx = threadIdx.x;
  for (int i = threadIdx.y; i < 32; i += 8) {
    int key = kb + i;
    if (key > L - 1) key = L - 1;
    tile[i][tx] = QKV[(size_t)(s * L + key) * 3072 + 2048 + h * 64 + cb + tx];
  }
  __syncthreads();
  for (int i = threadIdx.y; i < 32; i += 8)
    Vt[((size_t)sh * 64 + cb + i) * Lpad + kb + tx] = tile[tx][i];
}

// ================= 8-phase 256x256 GEMM (T3+T4 counted vmcnt, T2 swizzle, T5 setprio) ============
#define QROW(MI, AX)                                                                  \
  acc[MI][0] = __builtin_amdgcn_mfma_f32_16x16x32_bf16(AX, b0, acc[MI][0], 0, 0, 0);  \
  acc[MI][1] = __builtin_amdgcn_mfma_f32_16x16x32_bf16(AX, b1, acc[MI][1], 0, 0, 0);  \
  acc[MI][2] = __builtin_amdgcn_mfma_f32_16x16x32_bf16(AX, b2, acc[MI][2], 0, 0, 0);  \
  acc[MI][3] = __builtin_amdgcn_mfma_f32_16x16x32_bf16(AX, b3, acc[MI][3], 0, 0, 0);

#define RD12(B, S)                                                              \
  a0 = rdA(B, S, 0); a1 = rdA(B, S, 1); a2 = rdA(B, S, 2); a3 = rdA(B, S, 3);   \
  a4 = rdA(B, S, 4); a5 = rdA(B, S, 5); a6 = rdA(B, S, 6); a7 = rdA(B, S, 7);   \
  b0 = rdB(B, S, 0); b1 = rdB(B, S, 1); b2 = rdB(B, S, 2); b3 = rdB(B, S, 3);

__global__ __launch_bounds__(512, 2) void gemm_8ph(const short* __restrict__ A,
                                                   const short* __restrict__ BT,
                                                   short* __restrict__ C,
                                                   int K, int N) {
  extern __shared__ short lds[];      // 65536 shorts = 128KB
  short* Asb = lds;                   // [buf*2+half][8192]
  short* Bsb = lds + 32768;
  const int tid = threadIdx.x;
  const int lane = tid & 63, wid = tid >> 6;
  const int wm = wid >> 2, wn = wid & 3;  // 2 x 4 wave grid
  const int l15 = lane & 15, lhi = lane >> 4;
  const int m0 = blockIdx.y * 256;
  const int n0 = blockIdx.x * 256;

  f32x4 acc[8][4] = {};

  auto stageA = [&](int b, int h, int kt) {
#pragma unroll
    for (int j = 0; j < 2; ++j) {
      int u = j * 512 + tid;          // 0..1023
      int row = u >> 3, slot = u & 7;
      int ss = slot ^ (row & 7);      // inverse swizzle on source (involution)
      gl_lds16(A + (size_t)(m0 + h * 128 + row) * K + kt * 64 + ss * 8,
               Asb + (b * 2 + h) * 8192 + u * 8);
    }
  };
  auto stageB = [&](int b, int h, int kt) {
#pragma unroll
    for (int j = 0; j < 2; ++j) {
      int u = j * 512 + tid;
      int row = u >> 3, slot = u & 7;
      int ss = slot ^ (row & 7);
      gl_lds16(BT + (size_t)(n0 + h * 128 + row) * K + kt * 64 + ss * 8,
               Bsb + (b * 2 + h) * 8192 + u * 8);
    }
  };
  auto rdA = [&](int b, int s, int mf) -> s16x8 {
    int row = mf * 16 + l15;
    int sl = ((s << 2) | lhi) ^ (row & 7);
    return *(const s16x8*)(Asb + (b * 2 + wm) * 8192 + row * 64 + sl * 8);
  };
  auto rdB = [&](int b, int s, int nf) -> s16x8 {
    int row = (wn & 1) * 64 + nf * 16 + l15;
    int sl = ((s << 2) | lhi) ^ (row & 7);
    return *(const s16x8*)(Bsb + (b * 2 + (wn >> 1)) * 8192 + row * 64 + sl * 8);
  };

  const int NT = K >> 7;  // iterations; 2 K-tiles (BK=64) each

  stageA(0, 0, 0); stageA(0, 1, 0); stageB(0, 0, 0); stageB(0, 1, 0);
  stageA(1, 0, 1); stageA(1, 1, 1);
  asm volatile("s_waitcnt vmcnt(4)" ::: "memory");
  __builtin_amdgcn_s_barrier();

  s16x8 a0, a1, a2, a3, a4, a5, a6, a7, b0, b1, b2, b3;

  for (int t = 0; t < NT; ++t) {
    const bool last = (t == NT - 1);
    const int kt1 = 2 * t + 1;
    RD12(0, 0)
    stageB(1, 0, kt1);
    __builtin_amdgcn_s_barrier();
    __builtin_amdgcn_s_setprio(1);
    QROW(0, a0) QROW(1, a1) QROW(2, a2) QROW(3, a3)
    __builtin_amdgcn_s_setprio(0);
    __builtin_amdgcn_s_barrier();
    stageB(1, 1, kt1);
    __builtin_amdgcn_s_barrier();
    __builtin_amdgcn_s_setprio(1);
    QROW(4, a4) QROW(5, a5) QROW(6, a6) QROW(7, a7)
    __builtin_amdgcn_s_setprio(0);
    __builtin_amdgcn_s_barrier();
    RD12(0, 1)
    __builtin_amdgcn_s_barrier();
    __builtin_amdgcn_s_setprio(1);
    QROW(0, a0) QROW(1, a1) QROW(2, a2) QROW(3, a3)
    __builtin_amdgcn_s_setprio(0);
    __builtin_amdgcn_s_barrier();
    if (!last) {
      stageA(0, 0, 2 * t + 2); stageA(0, 1, 2 * t + 2);
      asm volatile("s_waitcnt vmcnt(4)" ::: "memory");
    } else {
      asm volatile("s_waitcnt vmcnt(0)" ::: "memory");
    }
    __builtin_amdgcn_s_barrier();
    __builtin_amdgcn_s_setprio(1);
    QROW(4, a4) QROW(5, a5) QROW(6, a6) QROW(7, a7)
    __builtin_amdgcn_s_setprio(0);
    __builtin_amdgcn_s_barrier();
    RD12(1, 0)
    if (!last) stageB(0, 0, 2 * t + 2);
    __builtin_amdgcn_s_barrier();
    __builtin_amdgcn_s_setprio(1);
    QROW(0, a0) QROW(1, a1) QROW(2, a2) QROW(3, a3)
    __builtin_amdgcn_s_setprio(0);
    __builtin_amdgcn_s_barrier();
    if (!last) stageB(0, 1, 2 * t + 2);
    __builtin_amdgcn_s_barrier();
    __builtin_amdgcn_s_setprio(1);
    QROW(4, a4) QROW(5, a5) QROW(6, a6) QROW(7, a7)
    __builtin_amdgcn_s_setprio(0);
    __builtin_amdgcn_s_barrier();
    RD12(1, 1)
    __builtin_amdgcn_s_barrier();
    __builtin_amdgcn_s_setprio(1);
    QROW(0, a0) QROW(1, a1) QROW(2, a2) QROW(3, a3)
    __builtin_amdgcn_s_setprio(0);
    __builtin_amdgcn_s_barrier();
    if (!last) {
      stageA(1, 0, kt1 + 2); stageA(1, 1, kt1 + 2);
      asm volatile("s_waitcnt vmcnt(4)" ::: "memory");
    }
    __builtin_amdgcn_s_barrier();
    __builtin_amdgcn_s_setprio(1);
    QROW(4, a4) QROW(5, a5) QROW(6, a6) QROW(7, a7)
    __builtin_amdgcn_s_setprio(0);
    __builtin_amdgcn_s_barrier();
  }

#pragma unroll
  for (int mf = 0; mf < 8; ++mf) {
    int row_base = m0 + wm * 128 + mf * 16 + lhi * 4;
#pragma unroll
    for (int nf = 0; nf < 4; ++nf) {
      int col = n0 + wn * 64 + nf * 16 + l15;
#pragma unroll
      for (int r = 0; r < 4; ++r)
        C[(size_t)(row_base + r) * N + col] = f2b(acc[mf][nf][r]);
    }
  }
}

// ---------------- GEMM v3 (2-phase prefetch; used for proj N=1024) ----------------
__global__ __launch_bounds__(256) void gemm_bt3(const short* __restrict__ A,
                                                const short* __restrict__ BT,
                                                short* __restrict__ C,
                                                int K, int N) {
  __shared__ short As[2][128 * 32];
  __shared__ short Bs[2][128 * 32];
  const int tid = threadIdx.x;
  const int lane = tid & 63;
  const int w = tid >> 6;
  const int wr = (w >> 1) * 64, wc = (w & 1) * 64;
  const int m0 = blockIdx.y * 128;
  const int n0 = blockIdx.x * 128;
  const int l15 = lane & 15, lhi = lane >> 4;

  f32x4 acc[4][4] = {};

  auto STAGE = [&](int b, int k0) {
#pragma unroll
    for (int p = 0; p < 2; ++p) {
      int g = w * 128 + p * 64 + lane;
      int row = g >> 2;
      int cs = (g & 3) * 8;
      gl_lds16(A + (size_t)(m0 + row) * K + k0 + cs, &As[b][g * 8]);
      gl_lds16(BT + (size_t)(n0 + row) * K + k0 + cs, &Bs[b][g * 8]);
    }
  };

  const int nt = K >> 5;
  STAGE(0, 0);
  __syncthreads();
  int cur = 0;
  for (int t = 0; t < nt; ++t) {
    if (t + 1 < nt) STAGE(cur ^ 1, (t + 1) << 5);
    s16x8 af[4], bf[4];
#pragma unroll
    for (int m = 0; m < 4; ++m)
      af[m] = *(const s16x8*)(&As[cur][(wr + m * 16 + l15) * 32 + lhi * 8]);
#pragma unroll
    for (int n = 0; n < 4; ++n)
      bf[n] = *(const s16x8*)(&Bs[cur][(wc + n * 16 + l15) * 32 + lhi * 8]);
#pragma unroll
    for (int m = 0; m < 4; ++m)
#pragma unroll
      for (int n = 0; n < 4; ++n)
        acc[m][n] = __builtin_amdgcn_mfma_f32_16x16x32_bf16(af[m], bf[n], acc[m][n], 0, 0, 0);
    __syncthreads();
    cur ^= 1;
  }
#pragma unroll
  for (int m = 0; m < 4; ++m) {
    int row_base = m0 + wr + m * 16 + lhi * 4;
#pragma unroll
    for (int n = 0; n < 4; ++n) {
      int col = n0 + wc + n * 16 + l15;
#pragma unroll
      for (int r = 0; r < 4; ++r)
        C[(size_t)(row_base + r) * N + col] = f2b(acc[m][n][r]);
    }
  }
}

// ---------------- RMSNorm on Q (with 1/8*log2e scale) and K slices of QKV, in place ----------------
__global__ __launch_bounds__(256) void rmsnorm_qk(short* __restrict__ QKV,
                                                  const float* __restrict__ g) {
  int row = blockIdx.x;
  int which = blockIdx.y;  // 0 = q, 1 = k
  size_t base = (size_t)row * 3072 + (size_t)which * 1024;
  int t = threadIdx.x;
  s16x4 in = *(const s16x4*)(QKV + base + t * 4);
  float v[4];
  float ss = 0.f;
#pragma unroll
  for (int j = 0; j < 4; ++j) {
    v[j] = b2f(in[j]);
    ss += v[j] * v[j];
  }
#pragma unroll
  for (int m = 32; m >= 1; m >>= 1) ss += __shfl_xor(ss, m);
  __shared__ float red[4];
  if ((t & 63) == 0) red[t >> 6] = ss;
  __syncthreads();
  float tot = red[0] + red[1] + red[2] + red[3];
  float inv = rsqrtf(tot * (1.0f / 1024.0f) + 1e-6f);
  if (which == 0) inv *= 0.125f * 1.44269504f;  // fold 1/sqrt(hd) AND log2(e) into Q
  s16x4 out;
#pragma unroll
  for (int j = 0; j < 4; ++j) out[j] = f2b(v[j] * inv * g[t * 4 + j]);
  *(s16x4*)(&QKV[base + t * 4]) = out;
}

// ======== swapped-operand attention (proven R12 form) ========
// QK^T computed as mfma(K, Q); P->bf16 via v_cvt_pk; PV A-fragment via 16 __shfl.
// Ks/Vs double-buffered, ONE barrier per iter, prefetch issued AFTER the barrier
// (loads stay in flight across the compute phase).

// ---------------- causal flash attention (local) ----------------
__global__ __launch_bounds__(256) void attn_causal4(const short* __restrict__ QKV,
                                                    const short* __restrict__ Vt,
                                                    short* __restrict__ Y,
                                                    int L, int Lpad) {
  const int h = blockIdx.y, s = blockIdx.z;
  const int q0 = blockIdx.x * 64;
  const int tid = threadIdx.x;
  const int lane = tid & 63, w = tid >> 6;
  const int l15 = lane & 15, lhi = lane >> 4;
  const int row0 = s * L;

  __shared__ short Ks[2][64][72];
  __shared__ short Vs[2][64][72];

  int qld = q0 + w * 16 + l15;
  if (qld > L - 1) qld = L - 1;
  const size_t qrow = (size_t)(row0 + qld) * 3072 + h * 64;
  s16x8 qf0 = *(const s16x8*)(QKV + qrow + lhi * 8);
  s16x8 qf1 = *(const s16x8*)(QKV + qrow + 32 + lhi * 8);

  float lsum = 0.f;
  f32x4 o[4];
#pragma unroll
  for (int d = 0; d < 4; ++d) o[d] = f32x4{0.f, 0.f, 0.f, 0.f};

  const short* Vbase = Vt + (size_t)(s * 16 + h) * 64 * Lpad;
  const int sA = (lhi & 1) * 32 + l15;
  const int sB = sA + 16;
  const int bh = lhi >> 1;

  s16x8 kreg[2], vreg[2];
#pragma unroll
  for (int p = 0; p < 2; ++p) {
    int g = tid + p * 256;
    int kr = g >> 3, cs = (g & 7) * 8;
    int krow = kr;
    if (krow > L - 1) krow = L - 1;
    kreg[p] = *(const s16x8*)(QKV + (size_t)(row0 + krow) * 3072 + 1024 + h * 64 + cs);
    vreg[p] = *(const s16x8*)(Vbase + (size_t)kr * Lpad + cs);
  }

  int buf = 0;
  for (int kb = 0; kb <= q0; kb += 64, buf ^= 1) {
#pragma unroll
    for (int p = 0; p < 2; ++p) {
      int g = tid + p * 256;
      int kr = g >> 3, cs = (g & 7) * 8;
      *(s16x8*)(&Ks[buf][kr][cs]) = kreg[p];
      *(s16x8*)(&Vs[buf][kr][cs]) = vreg[p];
    }
    __syncthreads();
    if (kb + 64 <= q0) {
#pragma unroll
      for (int p = 0; p < 2; ++p) {
        int g = tid + p * 256;
        int kr = g >> 3, cs = (g & 7) * 8;
        int krow = kb + 64 + kr;
        if (krow > L - 1) krow = L - 1;
        kreg[p] = *(const s16x8*)(QKV + (size_t)(row0 + krow) * 3072 + 1024 + h * 64 + cs);
        vreg[p] = *(const s16x8*)(Vbase + (size_t)kr * Lpad + kb + 64 + cs);
      }
    }

    f32x4 st[4];
#pragma unroll
    for (int n = 0; n < 4; ++n) {
      s16x8 k0 = *(const s16x8*)(&Ks[buf][n * 16 + l15][lhi * 8]);
      s16x8 k1 = *(const s16x8*)(&Ks[buf][n * 16 + l15][32 + lhi * 8]);
      f32x4 sa = f32x4{-SM_SHIFT, -SM_SHIFT, -SM_SHIFT, -SM_SHIFT};
      sa = __builtin_amdgcn_mfma_f32_16x16x32_bf16(k0, qf0, sa, 0, 0, 0);
      sa = __builtin_amdgcn_mfma_f32_16x16x32_bf16(k1, qf1, sa, 0, 0, 0);
      st[n] = sa;
    }

    if (kb == q0) {
      int q = q0 + w * 16 + l15;
#pragma unroll
      for (int n = 0; n < 4; ++n) {
#pragma unroll
        for (int r = 0; r < 4; ++r) {
          int key = kb + n * 16 + lhi * 4 + r;
          if (key > q) st[n][r] = -1e30f;
        }
      }
    }

    int wd[4][2];
#pragma unroll
    for (int n = 0; n < 4; ++n) {
      float p0 = fexp2(st[n][0]), p1 = fexp2(st[n][1]);
      float p2 = fexp2(st[n][2]), p3 = fexp2(st[n][3]);
      lsum += (p0 + p1) + (p2 + p3);
      wd[n][0] = cvtpk(p0, p1);
      wd[n][1] = cvtpk(p2, p3);
    }

#pragma unroll
    for (int kk = 0; kk < 2; ++kk) {
      int a0 = __shfl(wd[2 * kk][0], sA), a1 = __shfl(wd[2 * kk][1], sA);
      int a2 = __shfl(wd[2 * kk][0], sB), a3 = __shfl(wd[2 * kk][1], sB);
      int c0 = __shfl(wd[2 * kk + 1][0], sA), c1 = __shfl(wd[2 * kk + 1][1], sA);
      int c2 = __shfl(wd[2 * kk + 1][0], sB), c3 = __shfl(wd[2 * kk + 1][1], sB);
      int pw[4];
      pw[0] = bh ? c0 : a0;
      pw[1] = bh ? c1 : a1;
      pw[2] = bh ? c2 : a2;
      pw[3] = bh ? c3 : a3;
      s16x8 pa = *(const s16x8*)pw;
#pragma unroll
      for (int d = 0; d < 4; ++d) {
        s16x8 vf = *(const s16x8*)(&Vs[buf][d * 16 + l15][kk * 32 + lhi * 8]);
        o[d] = __builtin_amdgcn_mfma_f32_16x16x32_bf16(pa, vf, o[d], 0, 0, 0);
      }
    }
  }

  lsum += __shfl_xor(lsum, 16);
  lsum += __shfl_xor(lsum, 32);
  float lsq[4];
#pragma unroll
  for (int r = 0; r < 4; ++r) lsq[r] = __shfl(lsum, lhi * 4 + r);
#pragma unroll
  for (int d = 0; d < 4; ++d) {
#pragma unroll
    for (int r = 0; r < 4; ++r) {
      int qr = q0 + w * 16 + lhi * 4 + r;
      if (qr < L)
        Y[(size_t)(row0 + qr) * 1024 + h * 64 + d * 16 + l15] = f2b(o[d][r] / lsq[r]);
    }
  }
}

// ---------------- split-K causal attention (global, L=2064) ----------------
__global__ __launch_bounds__(256) void attn_split2(const short* __restrict__ QKV,
                                                   const short* __restrict__ Vt,
                                                   float* __restrict__ o_acc,
                                                   float* __restrict__ ls_acc) {
  const int qb = blockIdx.x;
  const int chunk = blockIdx.y;
  const int sh = blockIdx.z;
  const int t0 = chunk * CT;
  if (t0 > qb) return;
  const int t1 = min(t0 + CT, qb + 1);
  const int h = sh & 15, s = sh >> 4;
  const int q0 = qb * 64;
  const int tid = threadIdx.x;
  const int lane = tid & 63, w = tid >> 6;
  const int l15 = lane & 15, lhi = lane >> 4;
  const int row0 = s * LG;
  const int Lpad = 2112;

  __shared__ short Ks[2][64][72];
  __shared__ short Vs[2][64][72];

  int qld = q0 + w * 16 + l15;
  if (qld > LG - 1) qld = LG - 1;
  const size_t qrow = (size_t)(row0 + qld) * 3072 + h * 64;
  s16x8 qf0 = *(const s16x8*)(QKV + qrow + lhi * 8);
  s16x8 qf1 = *(const s16x8*)(QKV + qrow + 32 + lhi * 8);

  float lsum = 0.f;
  f32x4 o[4];
#pragma unroll
  for (int d = 0; d < 4; ++d) o[d] = f32x4{0.f, 0.f, 0.f, 0.f};

  const short* Vbase = Vt + (size_t)sh * 64 * Lpad;
  const int sA = (lhi & 1) * 32 + l15;
  const int sB = sA + 16;
  const int bh = lhi >> 1;

  s16x8 kreg[2], vreg[2];
  const int kb0 = t0 * 64;
#pragma unroll
  for (int p = 0; p < 2; ++p) {
    int g = tid + p * 256;
    int kr = g >> 3, cs = (g & 7) * 8;
    int krow = kb0 + kr;
    if (krow > LG - 1) krow = LG - 1;
    kreg[p] = *(const s16x8*)(QKV + (size_t)(row0 + krow) * 3072 + 1024 + h * 64 + cs);
    vreg[p] = *(const s16x8*)(Vbase + (size_t)kr * Lpad + kb0 + cs);
  }

  int buf = 0;
  for (int t = t0; t < t1; ++t, buf ^= 1) {
    const int kb = t * 64;
#pragma unroll
    for (int p = 0; p < 2; ++p) {
      int g = tid + p * 256;
      int kr = g >> 3, cs = (g & 7) * 8;
      *(s16x8*)(&Ks[buf][kr][cs]) = kreg[p];
      *(s16x8*)(&Vs[buf][kr][cs]) = vreg[p];
    }
    __syncthreads();
    if (t + 1 < t1) {
#pragma unroll
      for (int p = 0; p < 2; ++p) {
        int g = tid + p * 256;
        int kr = g >> 3, cs = (g & 7) * 8;
        int krow = kb + 64 + kr;
        if (krow > LG - 1) krow = LG - 1;
        kreg[p] = *(const s16x8*)(QKV + (size_t)(row0 + krow) * 3072 + 1024 + h * 64 + cs);
        vreg[p] = *(const s16x8*)(Vbase + (size_t)kr * Lpad + kb + 64 + cs);
      }
    }

    f32x4 st[4];
#pragma unroll
    for (int n = 0; n < 4; ++n) {
      s16x8 k0 = *(const s16x8*)(&Ks[buf][n * 16 + l15][lhi * 8]);
      s16x8 k1 = *(const s16x8*)(&Ks[buf][n * 16 + l15][32 + lhi * 8]);
      f32x4 sa = f32x4{-SM_SHIFT, -SM_SHIFT, -SM_SHIFT, -SM_SHIFT};
      sa = __builtin_amdgcn_mfma_f32_16x16x32_bf16(k0, qf0, sa, 0, 0, 0);
      sa = __builtin_amdgcn_mfma_f32_16x16x32_bf16(k1, qf1, sa, 0, 0, 0);
      st[n] = sa;
    }

    if (t == qb) {
      int q = q0 + w * 16 + l15;
#pragma unroll
      for (int n = 0; n < 4; ++n) {
#pragma unroll
        for (int r = 0; r < 4; ++r) {
          int key = kb + n * 16 + lhi * 4 + r;
          if (key > q) st[n][r] = -1e30f;
        }
      }
    }

    int wd[4][2];
#pragma unroll
    for (int n = 0; n < 4; ++n) {
      float p0 = fexp2(st[n][0]), p1 = fexp2(st[n][1]);
      float p2 = fexp2(st[n][2]), p3 = fexp2(st[n][3]);
      lsum += (p0 + p1) + (p2 + p3);
      wd[n][0] = cvtpk(p0, p1);
      wd[n][1] = cvtpk(p2, p3);
    }

#pragma unroll
    for (int kk = 0; kk < 2; ++kk) {
      int a0 = __shfl(wd[2 * kk][0], sA), a1 = __shfl(wd[2 * kk][1], sA);
      int a2 = __shfl(wd[2 * kk][0], sB), a3 = __shfl(wd[2 * kk][1], sB);
      int c0 = __shfl(wd[2 * kk + 1][0], sA), c1 = __shfl(wd[2 * kk + 1][1], sA);
      int c2 = __shfl(wd[2 * kk + 1][0], sB), c3 = __shfl(wd[2 * kk + 1][1], sB);
      int pw[4];
      pw[0] = bh ? c0 : a0;
      pw[1] = bh ? c1 : a1;
      pw[2] = bh ? c2 : a2;
      pw[3] = bh ? c3 : a3;
      s16x8 pa = *(const s16x8*)pw;
#pragma unroll
      for (int d = 0; d < 4; ++d) {
        s16x8 vf = *(const s16x8*)(&Vs[buf][d * 16 + l15][kk * 32 + lhi * 8]);
        o[d] = __builtin_amdgcn_mfma_f32_16x16x32_bf16(pa, vf, o[d], 0, 0, 0);
      }
    }
  }

  lsum += __shfl_xor(lsum, 16);
  lsum += __shfl_xor(lsum, 32);
  int qmy = q0 + w * 16 + l15;
  if (lhi == 0 && qmy < LG) atomicAdd(&ls_acc[(size_t)sh * LG + qmy], lsum);
#pragma unroll
  for (int r = 0; r < 4; ++r) {
    int qr = q0 + w * 16 + lhi * 4 + r;
    if (qr < LG) {
#pragma unroll
      for (int d = 0; d < 4; ++d)
        atomicAdd(&o_acc[((size_t)sh * LG + qr) * 64 + d * 16 + l15], o[d][r]);
    }
  }
}

// merge: Y = o_acc / ls_acc
__global__ __launch_bounds__(256) void attn_merge(const float* __restrict__ o_acc,
                                                  const float* __restrict__ ls_acc,
                                                  short* __restrict__ Y) {
  int sh = blockIdx.z * 16 + blockIdx.y;
  int s = sh >> 4, h = sh & 15;
  int row = blockIdx.x * 4 + (threadIdx.x >> 6);
  int col = threadIdx.x & 63;
  if (row < LG) {
    float inv = 1.0f / ls_acc[(size_t)sh * LG + row];
    float v = o_acc[((size_t)sh * LG + row) * 64 + col];
    Y[(size_t)(s * LG + row) * 1024 + h * 64 + col] = f2b(v * inv);
  }
}

// ---------------- fused gather/scatter ----------------
__global__ __launch_bounds__(256) void build_xl(const float* __restrict__ x,
                                                const float* __restrict__ lm,
                                                short* __restrict__ Xin) {
  int row = blockIdx.x;  // 0..4351
  int s = row / 272, r = row % 272;
  const float* src = (r < 16) ? lm + ((size_t)s * 16 + r) * 1024
                              : x + ((size_t)s * 256 + (r - 16)) * 1024;
  int t = threadIdx.x;
  f32x4 v = *(const f32x4*)(src + t * 4);
  s16x4 o;
#pragma unroll
  for (int j = 0; j < 4; ++j) o[j] = f2b(v[j]);
  *(s16x4*)(&Xin[(size_t)row * 1024 + t * 4]) = o;
}

__global__ __launch_bounds__(256) void split_local_build_xg(const short* __restrict__ Pout,
                                                            const float* __restrict__ mem_src,
                                                            float* __restrict__ lm_out,
                                                            short* __restrict__ Xin) {
  int row = blockIdx.x;
  int t = threadIdx.x;
  if (row < 4352) {
    int sr = row < 4128 ? row : 4127;
    int b = sr / 2064, r = sr % 2064;
    s16x4 o;
    if (r < 16) {
      f32x4 v = *(const f32x4*)(mem_src + ((size_t)(b * 16 + r)) * 1024 + t * 4);
#pragma unroll
      for (int j = 0; j < 4; ++j) o[j] = f2b(v[j]);
    } else {
      int f = b * 2048 + (r - 16);
      int pr = (f >> 8) * 272 + 16 + (f & 255);
      o = *(const s16x4*)(Pout + (size_t)pr * 1024 + t * 4);
    }
    *(s16x4*)(&Xin[(size_t)row * 1024 + t * 4]) = o;
  } else {
    int m = row - 4352;
    int pr = (m >> 4) * 272 + (m & 15);
    s16x4 v = *(const s16x4*)(Pout + (size_t)pr * 1024 + t * 4);
    f32x4 o;
#pragma unroll
    for (int j = 0; j < 4; ++j) o[j] = b2f(v[j]);
    *(f32x4*)(&lm_out[(size_t)m * 1024 + t * 4]) = o;
  }
}

__global__ __launch_bounds__(256) void split_global_build_xl(const short* __restrict__ Pout,
                                                             const float* __restrict__ lm_src,
                                                             float* __restrict__ mem_out,
                                                             short* __restrict__ Xin) {
  int row = blockIdx.x;
  int t = threadIdx.x;
  if (row < 4352) {
    int s = row / 272, r = row % 272;
    s16x4 o;
    if (r < 16) {
      f32x4 v = *(const f32x4*)(lm_src + ((size_t)(s * 16 + r)) * 1024 + t * 4);
#pragma unroll
      for (int j = 0; j < 4; ++j) o[j] = f2b(v[j]);
    } else {
      int f = s * 256 + (r - 16);
      int pr = (f >> 11) * 2064 + 16 + (f & 2047);
      o = *(const s16x4*)(Pout + (size_t)pr * 1024 + t * 4);
    }
    *(s16x4*)(&Xin[(size_t)row * 1024 + t * 4]) = o;
  } else {
    int m = row - 4352;
    int pr = (m >> 4) * 2064 + (m & 15);
    s16x4 v = *(const s16x4*)(Pout + (size_t)pr * 1024 + t * 4);
    f32x4 o;
#pragma unroll
    for (int j = 0; j < 4; ++j) o[j] = b2f(v[j]);
    *(f32x4*)(&mem_out[(size_t)m * 1024 + t * 4]) = o;
  }
}

__global__ __launch_bounds__(256) void split_global_final(const short* __restrict__ Pout,
                                                          float* __restrict__ out) {
  int f = blockIdx.x;
  int t = threadIdx.x;
  int pr = (f >> 11) * 2064 + 16 + (f & 2047);
  s16x4 v = *(const s16x4*)(Pout + (size_t)pr * 1024 + t * 4);
  f32x4 o;
#pragma unroll
  for (int j = 0; j < 4; ++j) o[j] = b2f(v[j]);
  *(f32x4*)(&out[(size_t)f * 1024 + t * 4]) = o;
}

// ---------------- orchestration ----------------
extern "C" void kernel_launch(void* const* d_in, const int* in_sizes, int n_in,
                              void* d_out, int out_size, void* d_ws, size_t ws_size,
                              hipStream_t stream) {
  const float* x_in = (const float*)d_in[0];
  const float* mem_in = (const float*)d_in[1];
  const float* lm_in = (const float*)d_in[2];
  const float* Wqkv_loc = (const float*)d_in[3];
  const float* Wproj_loc = (const float*)d_in[4];
  const float* g_loc = (const float*)d_in[5];
  const float* Wqkv_glob = (const float*)d_in[6];
  const float* Wproj_glob = (const float*)d_in[7];
  const float* g_glob = (const float*)d_in[8];

  static bool attr_set = false;
  if (!attr_set) {
    hipFuncSetAttribute((const void*)gemm_8ph,
                        hipFuncAttributeMaxDynamicSharedMemorySize, 131072);
    attr_set = true;
  }

  char* ws = (char*)d_ws;
  size_t off = 0;
  auto alloc = [&](size_t bytes) {
    char* p = ws + off;
    off += (bytes + 255) & ~(size_t)255;
    return p;
  };
  short* Wt = (short*)alloc((size_t)3072 * 1024 * 2);
  float* lm_cur = (float*)alloc((size_t)256 * 1024 * 4);
  float* mem_cur = (float*)alloc((size_t)32 * 1024 * 4);
  short* Xin = (short*)alloc((size_t)MPAD * 1024 * 2);
  short* QKVb = (short*)alloc((size_t)MPAD * 3072 * 2);
  short* Yb = (short*)alloc((size_t)MPAD * 1024 * 2);
  short* Pout = (short*)alloc((size_t)MPAD * 1024 * 2);
  short* Vtb = (short*)alloc((size_t)256 * 64 * 320 * 2);
  size_t oacc_bytes = (size_t)32 * LG * 64 * 4;
  size_t lacc_bytes = (size_t)32 * LG * 4;
  float* o_acc = (float*)alloc(oacc_bytes);
  float* ls_acc = (float*)alloc(lacc_bytes);
  const bool use_split = (ws_size >= off);

  for (int i = 0; i < 2; ++i) {
    // ---- local attention (16 seqs, L=272, rows = 4352 = MPAD) ----
    transpose_cast<<<dim3(96, 32), dim3(32, 8), 0, stream>>>(
        Wqkv_loc + (size_t)i * 1024 * 3072, Wt, 1024, 3072);
    if (i == 0) build_xl<<<4352, 256, 0, stream>>>(x_in, lm_in, Xin);
    gemm_8ph<<<dim3(12, 17), 512, 131072, stream>>>(Xin, Wt, QKVb, 1024, 3072);
    rmsnorm_qk<<<dim3(4352, 2), 256, 0, stream>>>(QKVb, g_loc + (size_t)i * 1024);
    transpose_v<<<dim3(10, 2, 256), dim3(32, 8), 0, stream>>>(QKVb, Vtb, 272, 320);
    attn_causal4<<<dim3(5, 16, 16), 256, 0, stream>>>(QKVb, Vtb, Yb, 272, 320);
    transpose_cast<<<dim3(32, 32), dim3(32, 8), 0, stream>>>(
        Wproj_loc + (size_t)i * 1024 * 1024, Wt, 1024, 1024);
    gemm_bt3<<<dim3(8, 34), 256, 0, stream>>>(Yb, Wt, Pout, 1024, 1024);
    split_local_build_xg<<<4608, 256, 0, stream>>>(Pout, i == 0 ? mem_in : mem_cur,
                                                   lm_cur, Xin);

    // ---- global attention (2 seqs, L=2064, rows = 4128; pads deterministic) ----
    transpose_cast<<<dim3(96, 32), dim3(32, 8), 0, stream>>>(
        Wqkv_glob + (size_t)i * 1024 * 3072, Wt, 1024, 3072);
    gemm_8ph<<<dim3(12, 17), 512, 131072, stream>>>(Xin, Wt, QKVb, 1024, 3072);
    rmsnorm_qk<<<dim3(4128, 2), 256, 0, stream>>>(QKVb, g_glob + (size_t)i * 1024);
    transpose_v<<<dim3(66, 2, 32), dim3(32, 8), 0, stream>>>(QKVb, Vtb, 2064, 2112);
    if (use_split) {
      hipMemsetAsync(o_acc, 0, oacc_bytes, stream);
      hipMemsetAsync(ls_acc, 0, lacc_bytes, stream);
      attn_split2<<<dim3(33, 5, 32), 256, 0, stream>>>(QKVb, Vtb, o_acc, ls_acc);
      attn_merge<<<dim3(516, 16, 2), 256, 0, stream>>>(o_acc, ls_acc, Yb);
    } else {
      attn_causal4<<<dim3(33, 16, 2), 256, 0, stream>>>(QKVb, Vtb, Yb, 2064, 2112);
    }
    transpose_cast<<<dim3(32, 32), dim3(32, 8), 0, stream>>>(
        Wproj_glob + (size_t)i * 1024 * 1024, Wt, 1024, 1024);
    gemm_bt3<<<dim3(8, 34), 256, 0, stream>>>(Yb, Wt, Pout, 1024, 1024);
    if (i == 0)
      split_global_build_xl<<<4384, 256, 0, stream>>>(Pout, lm_cur, mem_cur, Xin);
    else
      split_global_final<<<4096, 256, 0, stream>>>(Pout, (float*)d_out);
  }
}